// Round 9
// baseline (183.436 us; speedup 1.0000x reference)
//
#include <hip/hip_runtime.h>
#include <math.h>

#define NB 4
#define SL 1024
#define EMB 1024
#define NH 16
#define HD 64
#define QB 128

typedef __attribute__((ext_vector_type(8))) short bf16x8;
typedef __attribute__((ext_vector_type(4))) float f32x4;
typedef __attribute__((ext_vector_type(4))) unsigned u32x4;

// round-half-up f32->bf16 pack (inputs finite)
static __device__ __forceinline__ unsigned pk2(float a, float b) {
    unsigned x = __float_as_uint(a) + 0x8000u;
    unsigned y = __float_as_uint(b) + 0x8000u;
    return (x >> 16) | (y & 0xFFFF0000u);
}
static __device__ __forceinline__ float exp2_fast(float x) {
    float r; asm("v_exp_f32 %0, %1" : "=v"(r) : "v"(x)); return r;
}
// 2x f32 -> packed bf16 (RNE), single instruction
static __device__ __forceinline__ unsigned cvtpk(float a, float b) {
    unsigned r; asm("v_cvt_pk_bf16_f32 %0, %1, %2" : "=v"(r) : "v"(a), "v"(b)); return r;
}
static __device__ __forceinline__ void gload_lds16(const void* g, void* l) {
    __builtin_amdgcn_global_load_lds(
        (const __attribute__((address_space(1))) unsigned int*)g,
        (__attribute__((address_space(3))) unsigned int*)l, 16, 0, 0);
}

#define VMW(n) asm volatile("s_waitcnt vmcnt(" #n ")" ::: "memory")
#define MEMPIN() asm volatile("" ::: "memory")

// ---------------- Fused prep: W conv | K conv+split (xCSC) | V transpose | mask bitmask ----------------
__global__ __launch_bounds__(256) void prep(
    const float* __restrict__ W, unsigned short* __restrict__ Wb,
    const float* __restrict__ Kf, unsigned short* __restrict__ Kb,
    const float* __restrict__ V, unsigned short* __restrict__ Vt,
    const int* __restrict__ mask, unsigned long long* __restrict__ Mbt)
{
    __shared__ unsigned short sT[128 * 68];
    const int bid = blockIdx.x, tid = threadIdx.x;
    const float CSC = 0.125f * 1.44269504f;   // folded into K so scores are exp2-ready

    if (bid < 512) {
        int i = (bid * 256 + tid) * 8;
        float4 f0 = *(const float4*)&W[i];
        float4 f1 = *(const float4*)&W[i + 4];
        uint4 u = { pk2(f0.x,f0.y), pk2(f0.z,f0.w), pk2(f1.x,f1.y), pk2(f1.z,f1.w) };
        *(uint4*)&Wb[i] = u;
    } else if (bid < 2560) {
        int t = bid - 512;
        int b = t >> 9, h = (t >> 5) & 15, k0 = (t & 31) * 32;
        int r = tid >> 3, d = (tid & 7) * 8;
        const float* gp = &Kf[((size_t)(b * SL + k0 + r)) * EMB + h * HD + d];
        float4 f0 = *(const float4*)gp, f1 = *(const float4*)(gp + 4);
        uint4 u = { pk2(f0.x*CSC,f0.y*CSC), pk2(f0.z*CSC,f0.w*CSC),
                    pk2(f1.x*CSC,f1.y*CSC), pk2(f1.z*CSC,f1.w*CSC) };
        *(uint4*)&Kb[((size_t)((b * NH + h) * SL + k0 + r)) * HD + d] = u;
    } else if (bid < 3072) {
        int t = bid - 2560;
        int bh = t >> 3, kb = t & 7;
        int b = bh >> 4, h = bh & 15;
        int k0 = kb * 128;
        #pragma unroll
        for (int i = 0; i < 4; ++i) {
            int lin = (i * 256 + tid) * 8;
            int r = lin >> 6, d = lin & 63;
            const float* gp = &V[((size_t)(b * SL + k0 + r)) * EMB + h * HD + d];
            float4 f0 = *(const float4*)gp, f1 = *(const float4*)(gp + 4);
            uint2 u0 = { pk2(f0.x,f0.y), pk2(f0.z,f0.w) };
            uint2 u1 = { pk2(f1.x,f1.y), pk2(f1.z,f1.w) };
            *(uint2*)&sT[r * 68 + d]     = u0;
            *(uint2*)&sT[r * 68 + d + 4] = u1;
        }
        __syncthreads();
        #pragma unroll
        for (int p = 0; p < 4; ++p) {
            int d = p * 16 + (tid >> 4);
            int c = tid & 15;
            unsigned v[4];
            #pragma unroll
            for (int j = 0; j < 4; ++j) {
                unsigned lo = sT[(c * 8 + 2 * j) * 68 + d];
                unsigned hi = sT[(c * 8 + 2 * j + 1) * 68 + d];
                v[j] = lo | (hi << 16);
            }
            uint4 u = { v[0], v[1], v[2], v[3] };
            *(uint4*)&Vt[((size_t)(bh * HD + d)) * SL + k0 + c * 8] = u;
        }
    } else {
        int t = bid - 3072;
        int lane = tid & 63;
        #pragma unroll
        for (int r = 0; r < 4; ++r) {
            int wid = (t * 4 + (tid >> 6)) * 4 + r;
            int c = wid & 15, q = (wid >> 4) & 1023, bb = wid >> 14;
            int mv = mask[((size_t)bb * SL + q) * SL + c * 64 + lane];
            unsigned long long bits = __ballot(mv != 0);
            if (lane == 0) Mbt[((size_t)bb * 16 + c) * SL + q] = bits;
        }
    }
}

// ---------------- Flash attention v12: K-in-LDS, V-direct-from-global ----------------
// v11b structure (k-parity split, 32q/wave, pair staging, counted VMW(2))
// with V staging DELETED: the 4 waves of a parity group read identical V
// fragment addresses -> L1 serves the 8KB tile after one L2 fill (addressing
// proven in R4). Halves both LDS reads (8 b128/wave/tile) and gload_lds DMA
// fills (8KB/tile) -- the DS pipe was the modeled bottleneck. V frags dt{0,1}
// issued at iter top (oldest vmem: their implicit waits leave gK/mb in
// flight, preserving the VMW(2) invariant: per-iter order [V4][gK2][mb2]),
// dt{2,3} after softmax (VGPR cap 128 at 4 waves/SIMD). LDS 34.8KB.
__global__ __launch_bounds__(512, 4) void attn_mfma(
    const float* __restrict__ Q, const unsigned short* __restrict__ Kb,
    const unsigned short* __restrict__ Vt,
    const unsigned long long* __restrict__ Mbt,
    unsigned short* __restrict__ Oa)
{
    const int lin = blockIdx.x;
    const int xcd = lin & 7, slot = lin >> 3;
    const int bh = xcd * 8 + (slot >> 3);       // 8 bh per XCD
    const int q0 = (slot & 7) * QB;             // 8 q-tiles of that bh
    const int b = bh >> 4, h = bh & 15;
    const int tid = threadIdx.x;
    const int w = tid >> 6, lane = tid & 63;
    const int m16 = lane & 15, quad = lane >> 4;
    const int lr = lane >> 3, lc = lane & 7;
    const int grp = w >> 2;                     // 0: even tiles, 1: odd tiles
    const int wq = w & 3;                       // q-strip (32 rows each)
    const int srow = w * 8;                     // block-wide staging rows

    __shared__ __align__(16) unsigned short sAll[17408];    // 34.8 KB (K bufs 32KB; merge overlays)
    unsigned short* sKb = sAll;                 // 4 x 4096 shorts (K bufs)

    const size_t vbase = (size_t)(bh * HD) * SL;   // Vt row d, len SL
    const size_t kbase = (size_t)(bh * SL) * HD;   // Kb row k, len 64
    const unsigned long long* Mp = Mbt + (size_t)(b * 16) * SL + q0 + wq * 32 + m16;
    const unsigned short* Vp = Vt + vbase;

    // --- prologue: Q loads first (retired in-prologue), K pair {0,1}, masks ---
    float4 qf[2][4];
    #pragma unroll
    for (int u = 0; u < 2; ++u) {
        const float* qp = &Q[((size_t)(b * SL + q0 + wq * 32 + u * 16 + m16)) * EMB + h * HD + quad * 8];
        qf[u][0] = *(const float4*)qp;        qf[u][1] = *(const float4*)(qp + 4);
        qf[u][2] = *(const float4*)(qp + 32); qf[u][3] = *(const float4*)(qp + 36);
    }
    MEMPIN();
    gload_lds16(&Kb[kbase + (size_t)(srow + lr) * HD + (lc ^ lr) * 8],      &sKb[srow * 64]);
    gload_lds16(&Kb[kbase + (size_t)(64 + srow + lr) * HD + (lc ^ lr) * 8], &sKb[4096 + srow * 64]);
    MEMPIN();
    unsigned long long mbC0 = Mp[(size_t)grp * SL];
    unsigned long long mbC1 = Mp[(size_t)grp * SL + 16];
    unsigned long long mbN0 = 0, mbN1 = 0;
    MEMPIN();

    bf16x8 bQ[2][2];
    #pragma unroll
    for (int u = 0; u < 2; ++u) {
        u32x4 u0 = { pk2(qf[u][0].x,qf[u][0].y), pk2(qf[u][0].z,qf[u][0].w),
                     pk2(qf[u][1].x,qf[u][1].y), pk2(qf[u][1].z,qf[u][1].w) };
        u32x4 u1 = { pk2(qf[u][2].x,qf[u][2].y), pk2(qf[u][2].z,qf[u][2].w),
                     pk2(qf[u][3].x,qf[u][3].y), pk2(qf[u][3].z,qf[u][3].w) };
        bQ[u][0] = __builtin_bit_cast(bf16x8, u0);
        bQ[u][1] = __builtin_bit_cast(bf16x8, u1);
    }

    f32x4 O[2][4] = {};
    f32x4 lacc[2] = {};
    const short one_bf = (short)0x3F80;
    const bf16x8 ones = { one_bf, one_bf, one_bf, one_bf, one_bf, one_bf, one_bf, one_bf };

    for (int i = 0; i < 8; ++i) {
        VMW(2);                                  // my 2 K-gloads done; 2 mask loads in flight
        __builtin_amdgcn_s_barrier();
        __builtin_amdgcn_sched_barrier(0);

        const int t = 2 * i + grp;               // this wave's tile
        const unsigned short* vp = Vp + t * 64;

        // V frags dt=0,1 direct from global (oldest vmem this iter; L1-amortized)
        bf16x8 vf0 = *(const bf16x8*)&vp[(size_t)(m16) * SL + quad * 8];
        bf16x8 vf1 = *(const bf16x8*)&vp[(size_t)(m16) * SL + (4 + quad) * 8];
        bf16x8 vf2 = *(const bf16x8*)&vp[(size_t)(16 + m16) * SL + quad * 8];
        bf16x8 vf3 = *(const bf16x8*)&vp[(size_t)(16 + m16) * SL + (4 + quad) * 8];
        MEMPIN();

        if (i < 7) {
            const int tE = 2 * i + 2;
            gload_lds16(&Kb[kbase + (size_t)(tE * 64 + srow + lr) * HD + (lc ^ lr) * 8],
                        &sKb[(tE & 3) * 4096 + srow * 64]);
            gload_lds16(&Kb[kbase + (size_t)((tE + 1) * 64 + srow + lr) * HD + (lc ^ lr) * 8],
                        &sKb[((tE + 1) & 3) * 4096 + srow * 64]);
            MEMPIN();   // keep mb loads AFTER the K-gloads (vmcnt arithmetic)
            mbN0 = Mp[(size_t)(t + 2) * SL];
            mbN1 = Mp[(size_t)(t + 2) * SL + 16];
            MEMPIN();
        }

        const unsigned short* kc = &sKb[(t & 3) * 4096];

        // scores: S^T[64k][32q], K-frag loaded once, used for both q-strips
        f32x4 sc[2][4];
        __builtin_amdgcn_s_setprio(1);
        #pragma unroll
        for (int t4 = 0; t4 < 4; ++t4) {
            int krow = t4 * 16 + m16;
            bf16x8 a0 = *(const bf16x8*)&kc[krow * 64 + ((quad ^ (krow & 7)) * 8)];
            bf16x8 a1 = *(const bf16x8*)&kc[krow * 64 + (((4 + quad) ^ (krow & 7)) * 8)];
            f32x4 z = {0.f, 0.f, 0.f, 0.f};
            sc[0][t4] = __builtin_amdgcn_mfma_f32_16x16x32_bf16(a0, bQ[0][0], z,         0,0,0);
            sc[0][t4] = __builtin_amdgcn_mfma_f32_16x16x32_bf16(a1, bQ[0][1], sc[0][t4], 0,0,0);
            sc[1][t4] = __builtin_amdgcn_mfma_f32_16x16x32_bf16(a0, bQ[1][0], z,         0,0,0);
            sc[1][t4] = __builtin_amdgcn_mfma_f32_16x16x32_bf16(a1, bQ[1][1], sc[1][t4], 0,0,0);
        }
        __builtin_amdgcn_s_setprio(0);

        // exp2 (CSC pre-folded into K) + in-register redistribution + mask
        bf16x8 bP[2][2];
        #pragma unroll
        for (int u = 0; u < 2; ++u) {
            unsigned long long mb = u ? mbC1 : mbC0;
            unsigned s0 = ((unsigned)mb) >> (quad * 8);
            unsigned s1 = ((unsigned)(mb >> 32)) >> (quad * 8);
            unsigned wt[4][2];
            #pragma unroll
            for (int t4 = 0; t4 < 4; ++t4) {
                wt[t4][0] = cvtpk(exp2_fast(sc[u][t4][0]), exp2_fast(sc[u][t4][1]));
                wt[t4][1] = cvtpk(exp2_fast(sc[u][t4][2]), exp2_fast(sc[u][t4][3]));
            }
            unsigned g[2][4];
            #pragma unroll
            for (int hh = 0; hh < 2; ++hh)
                #pragma unroll
                for (int p = 0; p < 2; ++p) {
                    unsigned A = wt[2 * hh][p], B = wt[2 * hh + 1][p];
                    asm("v_permlane32_swap_b32 %0, %1" : "+v"(A), "+v"(B));
                    asm("v_permlane16_swap_b32 %0, %1" : "+v"(A), "+v"(B));
                    g[hh][p] = A; g[hh][2 + p] = B;
                }
            #pragma unroll
            for (int hh = 0; hh < 2; ++hh) {
                unsigned sb = hh ? s1 : s0;
                #pragma unroll
                for (int j2 = 0; j2 < 4; ++j2) {
                    unsigned mlo = (unsigned)(((int)(sb << (31 - 2 * j2))) >> 31);
                    unsigned mhi = (unsigned)(((int)(sb << (30 - 2 * j2))) >> 31);
                    g[hh][j2] &= (mlo & 0xFFFFu) | (mhi & 0xFFFF0000u);
                }
            }
            u32x4 p0 = { g[0][0], g[0][1], g[0][2], g[0][3] };
            u32x4 p1 = { g[1][0], g[1][1], g[1][2], g[1][3] };
            bP[u][0] = __builtin_bit_cast(bf16x8, p0);
            bP[u][1] = __builtin_bit_cast(bf16x8, p1);
        }

        // V frags dt=2,3 (issued post-softmax to cap VGPR; gK/mb are ~500cy old
        // by first consumption, so the in-order drain they imply is cheap)
        bf16x8 vg0 = *(const bf16x8*)&vp[(size_t)(32 + m16) * SL + quad * 8];
        bf16x8 vg1 = *(const bf16x8*)&vp[(size_t)(32 + m16) * SL + (4 + quad) * 8];
        bf16x8 vg2 = *(const bf16x8*)&vp[(size_t)(48 + m16) * SL + quad * 8];
        bf16x8 vg3 = *(const bf16x8*)&vp[(size_t)(48 + m16) * SL + (4 + quad) * 8];
        MEMPIN();

        __builtin_amdgcn_s_setprio(1);
        // l partial: lacc += 1^T P
        lacc[0] = __builtin_amdgcn_mfma_f32_16x16x32_bf16(ones, bP[0][0], lacc[0], 0,0,0);
        lacc[0] = __builtin_amdgcn_mfma_f32_16x16x32_bf16(ones, bP[0][1], lacc[0], 0,0,0);
        lacc[1] = __builtin_amdgcn_mfma_f32_16x16x32_bf16(ones, bP[1][0], lacc[1], 0,0,0);
        lacc[1] = __builtin_amdgcn_mfma_f32_16x16x32_bf16(ones, bP[1][1], lacc[1], 0,0,0);

        // PV partial: O^T[64d][32q] += V^T P (V frags from registers)
        O[0][0] = __builtin_amdgcn_mfma_f32_16x16x32_bf16(vf0, bP[0][0], O[0][0], 0,0,0);
        O[0][0] = __builtin_amdgcn_mfma_f32_16x16x32_bf16(vf1, bP[0][1], O[0][0], 0,0,0);
        O[1][0] = __builtin_amdgcn_mfma_f32_16x16x32_bf16(vf0, bP[1][0], O[1][0], 0,0,0);
        O[1][0] = __builtin_amdgcn_mfma_f32_16x16x32_bf16(vf1, bP[1][1], O[1][0], 0,0,0);
        O[0][1] = __builtin_amdgcn_mfma_f32_16x16x32_bf16(vf2, bP[0][0], O[0][1], 0,0,0);
        O[0][1] = __builtin_amdgcn_mfma_f32_16x16x32_bf16(vf3, bP[0][1], O[0][1], 0,0,0);
        O[1][1] = __builtin_amdgcn_mfma_f32_16x16x32_bf16(vf2, bP[1][0], O[1][1], 0,0,0);
        O[1][1] = __builtin_amdgcn_mfma_f32_16x16x32_bf16(vf3, bP[1][1], O[1][1], 0,0,0);
        O[0][2] = __builtin_amdgcn_mfma_f32_16x16x32_bf16(vg0, bP[0][0], O[0][2], 0,0,0);
        O[0][2] = __builtin_amdgcn_mfma_f32_16x16x32_bf16(vg1, bP[0][1], O[0][2], 0,0,0);
        O[1][2] = __builtin_amdgcn_mfma_f32_16x16x32_bf16(vg0, bP[1][0], O[1][2], 0,0,0);
        O[1][2] = __builtin_amdgcn_mfma_f32_16x16x32_bf16(vg1, bP[1][1], O[1][2], 0,0,0);
        O[0][3] = __builtin_amdgcn_mfma_f32_16x16x32_bf16(vg2, bP[0][0], O[0][3], 0,0,0);
        O[0][3] = __builtin_amdgcn_mfma_f32_16x16x32_bf16(vg3, bP[0][1], O[0][3], 0,0,0);
        O[1][3] = __builtin_amdgcn_mfma_f32_16x16x32_bf16(vg2, bP[1][0], O[1][3], 0,0,0);
        O[1][3] = __builtin_amdgcn_mfma_f32_16x16x32_bf16(vg3, bP[1][1], O[1][3], 0,0,0);
        __builtin_amdgcn_s_setprio(0);

        mbC0 = mbN0; mbC1 = mbN1;
    }

    // --- merge the two k-parity partials (group B -> LDS, group A adds) ---
    __syncthreads();
    float* sM = (float*)sAll;   // planes: 8 x [256 lanes x f32x4] + l: 256 x 2 f32 = 34.8 KB
    if (grp == 1) {
        #pragma unroll
        for (int u = 0; u < 2; ++u)
            #pragma unroll
            for (int dt = 0; dt < 4; ++dt)
                *(f32x4*)&sM[((u * 4 + dt) * 256 + wq * 64 + lane) * 4] = O[u][dt];
        sM[8192 + (wq * 64 + lane) * 2 + 0] = lacc[0][0];
        sM[8192 + (wq * 64 + lane) * 2 + 1] = lacc[1][0];
    }
    __syncthreads();
    if (grp == 0) {
        float l[2];
        l[0] = lacc[0][0] + sM[8192 + (wq * 64 + lane) * 2 + 0];
        l[1] = lacc[1][0] + sM[8192 + (wq * 64 + lane) * 2 + 1];
        #pragma unroll
        for (int u = 0; u < 2; ++u) {
            float inv = 1.f / l[u];
            size_t base = ((size_t)(b * SL + q0 + wq * 32 + u * 16 + m16)) * EMB + h * HD + quad * 4;
            #pragma unroll
            for (int dt = 0; dt < 4; ++dt) {
                f32x4 part = *(const f32x4*)&sM[((u * 4 + dt) * 256 + wq * 64 + lane) * 4];
                f32x4 o = O[u][dt] + part;
                uint2 ow = { cvtpk(o[0] * inv, o[1] * inv),
                             cvtpk(o[2] * inv, o[3] * inv) };
                *(uint2*)&Oa[base + dt * 16] = ow;
            }
        }
    }
}

// ---------------- Projection v3: C[4096][1024] = A_bf16 @ W_bf16^T + bias ----------------
// (unchanged from R8 — depth-2 counted-vmcnt pipeline)
__global__ __launch_bounds__(256, 2) void proj_mfma(
    const unsigned short* __restrict__ A, const unsigned short* __restrict__ Wb,
    const float* __restrict__ bias, float* __restrict__ C)
{
    const int lin = blockIdx.x;
    const int xcd = lin & 7, idx = lin >> 3;
    const int m0 = (xcd * 4 + (idx >> 4)) * 128;   // 32 m-tiles
    const int n0 = (idx & 15) * 64;                // 16 n-tiles
    const int tid = threadIdx.x;
    const int w = tid >> 6, lane = tid & 63;
    const int m16 = lane & 15, quad = lane >> 4;
    const int lr = lane >> 3, lc = lane & 7;
    const int wm = (w >> 1) * 64, wn = (w & 1) * 32;

    __shared__ __align__(16) unsigned short sA[3][128 * 64];
    __shared__ __align__(16) unsigned short sW[3][64 * 64];

    f32x4 acc[4][2] = {};

    #define PSTAGE(IT, BI)                                                        \
    {                                                                             \
        const int e0_ = (IT) * 64;                                                \
        _Pragma("unroll")                                                         \
        for (int i_ = 0; i_ < 4; ++i_) {                                          \
            int r_ = w * 32 + i_ * 8;                                             \
            gload_lds16(&A[(size_t)(m0 + r_ + lr) * EMB + e0_ + (lc ^ lr) * 8],   \
                        &sA[BI][r_ * 64]);                                        \
        }                                                                         \
        _Pragma("unroll")                                                         \
        for (int i_ = 0; i_ < 2; ++i_) {                                          \
            int r_ = w * 16 + i_ * 8;                                             \
            gload_lds16(&Wb[(size_t)(n0 + r_ + lr) * EMB + e0_ + (lc ^ lr) * 8],  \
                        &sW[BI][r_ * 64]);                                        \
        }                                                                         \
    }

    PSTAGE(0, 0)
    MEMPIN();          // pin issue order: it0's 6 strictly older than it1's 6
    PSTAGE(1, 1)
    MEMPIN();

    for (int it = 0; it < 16; ++it) {
        if (it < 15) { VMW(6); } else { VMW(0); }   // my 6 for this iter retired
        __builtin_amdgcn_s_barrier();
        __builtin_amdgcn_sched_barrier(0);

        if (it < 14) {
            const int bn = (it + 2) % 3;
            PSTAGE(it + 2, bn)
            MEMPIN();
        }

        const int bf = it % 3;
        #pragma unroll
        for (int hh = 0; hh < 2; ++hh) {
            bf16x8 af[4], bw[2];
            #pragma unroll
            for (int mt = 0; mt < 4; ++mt) {
                int r = wm + mt * 16 + m16;
                af[mt] = *(const bf16x8*)&sA[bf][r * 64 + (((hh * 4 + quad) ^ (r & 7)) * 8)];
            }
            #pragma unroll
            for (int nt = 0; nt < 2; ++nt) {
                int r = wn + nt * 16 + m16;
                bw[nt] = *(const bf16x8*)&sW[bf][r * 64 + (((hh * 4 + quad) ^ (r & 7)) * 8)];
            }
            #pragma unroll
            for (int mt = 0; mt < 4; ++mt)
                #pragma unroll
                for (int nt = 0; nt < 2; ++nt)
                    acc[mt][nt] = __builtin_amdgcn_mfma_f32_16x16x32_bf16(af[mt], bw[nt], acc[mt][nt], 0,0,0);
        }
    }

    #pragma unroll
    for (int nt = 0; nt < 2; ++nt) {
        float bv = bias[n0 + wn + nt * 16 + m16];
        #pragma unroll
        for (int mt = 0; mt < 4; ++mt) {
            size_t row = (size_t)(m0 + wm + mt * 16 + quad * 4);
            #pragma unroll
            for (int rg = 0; rg < 4; ++rg)
                C[(row + rg) * EMB + n0 + wn + nt * 16 + m16] = acc[mt][nt][rg] + bv;
        }
    }
}

extern "C" void kernel_launch(void* const* d_in, const int* in_sizes, int n_in,
                              void* d_out, int out_size, void* d_ws, size_t ws_size,
                              hipStream_t stream) {
    const float* Q    = (const float*)d_in[0];
    const float* K    = (const float*)d_in[1];
    const float* V    = (const float*)d_in[2];
    const int*   mask = (const int*)  d_in[3];
    const float* W    = (const float*)d_in[4];
    const float* bias = (const float*)d_in[5];

    unsigned short* Oa = (unsigned short*)d_ws;                              // 8.39 MB
    unsigned short* Wb = Oa + (size_t)NB * SL * EMB;                         // 2.10 MB
    unsigned long long* Mbt = (unsigned long long*)(Wb + (size_t)EMB * EMB); // 0.52 MB
    unsigned short* Vt = (unsigned short*)(Mbt + (size_t)NB * 16 * SL);      // 8.39 MB
    unsigned short* Kb = Vt + (size_t)NB * NH * HD * SL;                     // 8.39 MB

    prep<<<7168, 256, 0, stream>>>(W, Wb, K, Kb, V, Vt, mask, Mbt);
    attn_mfma<<<512, 512, 0, stream>>>(Q, Kb, Vt, Mbt, Oa);
    proj_mfma<<<512, 256, 0, stream>>>(Oa, Wb, bias, (float*)d_out);
}

// Round 10
// 149.924 us; speedup vs baseline: 1.2235x; 1.2235x over previous
//
#include <hip/hip_runtime.h>
#include <math.h>

#define NB 4
#define SL 1024
#define EMB 1024
#define NH 16
#define HD 64
#define QB 128

typedef __attribute__((ext_vector_type(8))) short bf16x8;
typedef __attribute__((ext_vector_type(4))) float f32x4;
typedef __attribute__((ext_vector_type(4))) unsigned u32x4;

// round-half-up f32->bf16 pack (inputs finite)
static __device__ __forceinline__ unsigned pk2(float a, float b) {
    unsigned x = __float_as_uint(a) + 0x8000u;
    unsigned y = __float_as_uint(b) + 0x8000u;
    return (x >> 16) | (y & 0xFFFF0000u);
}
static __device__ __forceinline__ float exp2_fast(float x) {
    float r; asm("v_exp_f32 %0, %1" : "=v"(r) : "v"(x)); return r;
}
// 2x f32 -> packed bf16 (RNE), single instruction
static __device__ __forceinline__ unsigned cvtpk(float a, float b) {
    unsigned r; asm("v_cvt_pk_bf16_f32 %0, %1, %2" : "=v"(r) : "v"(a), "v"(b)); return r;
}
static __device__ __forceinline__ void gload_lds16(const void* g, void* l) {
    __builtin_amdgcn_global_load_lds(
        (const __attribute__((address_space(1))) unsigned int*)g,
        (__attribute__((address_space(3))) unsigned int*)l, 16, 0, 0);
}

#define VMW(n) asm volatile("s_waitcnt vmcnt(" #n ")" ::: "memory")
#define MEMPIN() asm volatile("" ::: "memory")

// ---------------- Fused prep: W conv | K conv+split (xCSC) | V transpose | mask bitmask ----------------
__global__ __launch_bounds__(256) void prep(
    const float* __restrict__ W, unsigned short* __restrict__ Wb,
    const float* __restrict__ Kf, unsigned short* __restrict__ Kb,
    const float* __restrict__ V, unsigned short* __restrict__ Vt,
    const int* __restrict__ mask, unsigned long long* __restrict__ Mbt)
{
    __shared__ unsigned short sT[128 * 68];
    const int bid = blockIdx.x, tid = threadIdx.x;
    const float CSC = 0.125f * 1.44269504f;   // folded into K so scores are exp2-ready

    if (bid < 512) {
        int i = (bid * 256 + tid) * 8;
        float4 f0 = *(const float4*)&W[i];
        float4 f1 = *(const float4*)&W[i + 4];
        uint4 u = { pk2(f0.x,f0.y), pk2(f0.z,f0.w), pk2(f1.x,f1.y), pk2(f1.z,f1.w) };
        *(uint4*)&Wb[i] = u;
    } else if (bid < 2560) {
        int t = bid - 512;
        int b = t >> 9, h = (t >> 5) & 15, k0 = (t & 31) * 32;
        int r = tid >> 3, d = (tid & 7) * 8;
        const float* gp = &Kf[((size_t)(b * SL + k0 + r)) * EMB + h * HD + d];
        float4 f0 = *(const float4*)gp, f1 = *(const float4*)(gp + 4);
        uint4 u = { pk2(f0.x*CSC,f0.y*CSC), pk2(f0.z*CSC,f0.w*CSC),
                    pk2(f1.x*CSC,f1.y*CSC), pk2(f1.z*CSC,f1.w*CSC) };
        *(uint4*)&Kb[((size_t)((b * NH + h) * SL + k0 + r)) * HD + d] = u;
    } else if (bid < 3072) {
        int t = bid - 2560;
        int bh = t >> 3, kb = t & 7;
        int b = bh >> 4, h = bh & 15;
        int k0 = kb * 128;
        #pragma unroll
        for (int i = 0; i < 4; ++i) {
            int lin = (i * 256 + tid) * 8;
            int r = lin >> 6, d = lin & 63;
            const float* gp = &V[((size_t)(b * SL + k0 + r)) * EMB + h * HD + d];
            float4 f0 = *(const float4*)gp, f1 = *(const float4*)(gp + 4);
            uint2 u0 = { pk2(f0.x,f0.y), pk2(f0.z,f0.w) };
            uint2 u1 = { pk2(f1.x,f1.y), pk2(f1.z,f1.w) };
            *(uint2*)&sT[r * 68 + d]     = u0;
            *(uint2*)&sT[r * 68 + d + 4] = u1;
        }
        __syncthreads();
        #pragma unroll
        for (int p = 0; p < 4; ++p) {
            int d = p * 16 + (tid >> 4);
            int c = tid & 15;
            unsigned v[4];
            #pragma unroll
            for (int j = 0; j < 4; ++j) {
                unsigned lo = sT[(c * 8 + 2 * j) * 68 + d];
                unsigned hi = sT[(c * 8 + 2 * j + 1) * 68 + d];
                v[j] = lo | (hi << 16);
            }
            uint4 u = { v[0], v[1], v[2], v[3] };
            *(uint4*)&Vt[((size_t)(bh * HD + d)) * SL + k0 + c * 8] = u;
        }
    } else {
        int t = bid - 3072;
        int lane = tid & 63;
        #pragma unroll
        for (int r = 0; r < 4; ++r) {
            int wid = (t * 4 + (tid >> 6)) * 4 + r;
            int c = wid & 15, q = (wid >> 4) & 1023, bb = wid >> 14;
            int mv = mask[((size_t)bb * SL + q) * SL + c * 64 + lane];
            unsigned long long bits = __ballot(mv != 0);
            if (lane == 0) Mbt[((size_t)bb * 16 + c) * SL + q] = bits;
        }
    }
}

// ---------------- Flash attention v11b: k-parity split, 32q/wave, 16 waves/CU ----------------
// (exact R8 revert — best harness-verified attn. R9's V-direct variant
// regressed 37->64us: vmcnt retires IN ORDER, so the post-softmax V register
// loads forced a full drain of the K prefetch every iteration, plus +7MB HBM
// V re-fetch. K/V both stay in LDS; counted VMW(2) leaves mask loads in
// flight across the barrier.)
__global__ __launch_bounds__(512, 4) void attn_mfma(
    const float* __restrict__ Q, const unsigned short* __restrict__ Kb,
    const unsigned short* __restrict__ Vt,
    const unsigned long long* __restrict__ Mbt,
    unsigned short* __restrict__ Oa)
{
    const int lin = blockIdx.x;
    const int xcd = lin & 7, slot = lin >> 3;
    const int bh = xcd * 8 + (slot >> 3);       // 8 bh per XCD
    const int q0 = (slot & 7) * QB;             // 8 q-tiles of that bh
    const int b = bh >> 4, h = bh & 15;
    const int tid = threadIdx.x;
    const int w = tid >> 6, lane = tid & 63;
    const int m16 = lane & 15, quad = lane >> 4;
    const int lr = lane >> 3, lc = lane & 7;
    const int grp = w >> 2;                     // 0: even tiles, 1: odd tiles
    const int wq = w & 3;                       // q-strip (32 rows each)
    const int srow = w * 8;                     // block-wide staging rows

    __shared__ __align__(16) unsigned short sAll[32768];    // 64 KB
    unsigned short* sKb = sAll;                 // 4 x 4096 shorts (K bufs)
    unsigned short* sVb = sAll + 16384;         // 4 x 4096 shorts (V bufs)

    const size_t vbase = (size_t)(bh * HD) * SL;   // Vt row d, len SL
    const size_t kbase = (size_t)(bh * SL) * HD;   // Kb row k, len 64
    const unsigned long long* Mp = Mbt + (size_t)(b * 16) * SL + q0 + wq * 32 + m16;

    // --- prologue: Q loads first (oldest vmem), then stage tiles 0,1 + masks ---
    float4 qf[2][4];
    #pragma unroll
    for (int u = 0; u < 2; ++u) {
        const float* qp = &Q[((size_t)(b * SL + q0 + wq * 32 + u * 16 + m16)) * EMB + h * HD + quad * 8];
        qf[u][0] = *(const float4*)qp;        qf[u][1] = *(const float4*)(qp + 4);
        qf[u][2] = *(const float4*)(qp + 32); qf[u][3] = *(const float4*)(qp + 36);
    }
    MEMPIN();
    #pragma unroll
    for (int t2 = 0; t2 < 2; ++t2) {
        gload_lds16(&Vt[vbase + (size_t)(srow + lr) * SL + t2 * 64 + (lc ^ lr) * 8],
                    &sVb[t2 * 4096 + srow * 64]);
        gload_lds16(&Kb[kbase + (size_t)(t2 * 64 + srow + lr) * HD + (lc ^ lr) * 8],
                    &sKb[t2 * 4096 + srow * 64]);
    }
    MEMPIN();
    unsigned long long mbC0 = Mp[(size_t)grp * SL];
    unsigned long long mbC1 = Mp[(size_t)grp * SL + 16];
    unsigned long long mbN0 = 0, mbN1 = 0;
    MEMPIN();

    bf16x8 bQ[2][2];
    #pragma unroll
    for (int u = 0; u < 2; ++u) {
        u32x4 u0 = { pk2(qf[u][0].x,qf[u][0].y), pk2(qf[u][0].z,qf[u][0].w),
                     pk2(qf[u][1].x,qf[u][1].y), pk2(qf[u][1].z,qf[u][1].w) };
        u32x4 u1 = { pk2(qf[u][2].x,qf[u][2].y), pk2(qf[u][2].z,qf[u][2].w),
                     pk2(qf[u][3].x,qf[u][3].y), pk2(qf[u][3].z,qf[u][3].w) };
        bQ[u][0] = __builtin_bit_cast(bf16x8, u0);
        bQ[u][1] = __builtin_bit_cast(bf16x8, u1);
    }

    f32x4 O[2][4] = {};
    f32x4 lacc[2] = {};
    const short one_bf = (short)0x3F80;
    const bf16x8 ones = { one_bf, one_bf, one_bf, one_bf, one_bf, one_bf, one_bf, one_bf };

    for (int i = 0; i < 8; ++i) {
        VMW(2);                                  // my 4 gloads done; 2 mask loads stay in flight
        __builtin_amdgcn_s_barrier();            // everyone's gloads done; buffers for pair i ready
        __builtin_amdgcn_sched_barrier(0);

        const int t = 2 * i + grp;               // this wave's tile
        if (i < 7) {
            const int tE = 2 * i + 2;
            const int bE = tE & 3, bO = (tE + 1) & 3;
            gload_lds16(&Vt[vbase + (size_t)(srow + lr) * SL + tE * 64 + (lc ^ lr) * 8],
                        &sVb[bE * 4096 + srow * 64]);
            gload_lds16(&Kb[kbase + (size_t)(tE * 64 + srow + lr) * HD + (lc ^ lr) * 8],
                        &sKb[bE * 4096 + srow * 64]);
            gload_lds16(&Vt[vbase + (size_t)(srow + lr) * SL + (tE + 1) * 64 + (lc ^ lr) * 8],
                        &sVb[bO * 4096 + srow * 64]);
            gload_lds16(&Kb[kbase + (size_t)((tE + 1) * 64 + srow + lr) * HD + (lc ^ lr) * 8],
                        &sKb[bO * 4096 + srow * 64]);
            MEMPIN();   // keep mb loads AFTER the gloads (vmcnt arithmetic)
            mbN0 = Mp[(size_t)(t + 2) * SL];
            mbN1 = Mp[(size_t)(t + 2) * SL + 16];
            MEMPIN();
        }

        const unsigned short* kc = &sKb[(t & 3) * 4096];
        const unsigned short* vc = &sVb[(t & 3) * 4096];

        // scores: S^T[64k][32q], K-frag loaded once, used for both q-strips
        f32x4 sc[2][4];
        __builtin_amdgcn_s_setprio(1);
        #pragma unroll
        for (int t4 = 0; t4 < 4; ++t4) {
            int krow = t4 * 16 + m16;
            bf16x8 a0 = *(const bf16x8*)&kc[krow * 64 + ((quad ^ (krow & 7)) * 8)];
            bf16x8 a1 = *(const bf16x8*)&kc[krow * 64 + (((4 + quad) ^ (krow & 7)) * 8)];
            f32x4 z = {0.f, 0.f, 0.f, 0.f};
            sc[0][t4] = __builtin_amdgcn_mfma_f32_16x16x32_bf16(a0, bQ[0][0], z,         0,0,0);
            sc[0][t4] = __builtin_amdgcn_mfma_f32_16x16x32_bf16(a1, bQ[0][1], sc[0][t4], 0,0,0);
            sc[1][t4] = __builtin_amdgcn_mfma_f32_16x16x32_bf16(a0, bQ[1][0], z,         0,0,0);
            sc[1][t4] = __builtin_amdgcn_mfma_f32_16x16x32_bf16(a1, bQ[1][1], sc[1][t4], 0,0,0);
        }
        __builtin_amdgcn_s_setprio(0);

        // exp2 (CSC pre-folded into K) + in-register redistribution + mask
        bf16x8 bP[2][2];
        #pragma unroll
        for (int u = 0; u < 2; ++u) {
            unsigned long long mb = u ? mbC1 : mbC0;
            unsigned s0 = ((unsigned)mb) >> (quad * 8);
            unsigned s1 = ((unsigned)(mb >> 32)) >> (quad * 8);
            unsigned wt[4][2];
            #pragma unroll
            for (int t4 = 0; t4 < 4; ++t4) {
                wt[t4][0] = cvtpk(exp2_fast(sc[u][t4][0]), exp2_fast(sc[u][t4][1]));
                wt[t4][1] = cvtpk(exp2_fast(sc[u][t4][2]), exp2_fast(sc[u][t4][3]));
            }
            unsigned g[2][4];
            #pragma unroll
            for (int hh = 0; hh < 2; ++hh)
                #pragma unroll
                for (int p = 0; p < 2; ++p) {
                    unsigned A = wt[2 * hh][p], B = wt[2 * hh + 1][p];
                    asm("v_permlane32_swap_b32 %0, %1" : "+v"(A), "+v"(B));
                    asm("v_permlane16_swap_b32 %0, %1" : "+v"(A), "+v"(B));
                    g[hh][p] = A; g[hh][2 + p] = B;
                }
            #pragma unroll
            for (int hh = 0; hh < 2; ++hh) {
                unsigned sb = hh ? s1 : s0;
                #pragma unroll
                for (int j2 = 0; j2 < 4; ++j2) {
                    unsigned mlo = (unsigned)(((int)(sb << (31 - 2 * j2))) >> 31);
                    unsigned mhi = (unsigned)(((int)(sb << (30 - 2 * j2))) >> 31);
                    g[hh][j2] &= (mlo & 0xFFFFu) | (mhi & 0xFFFF0000u);
                }
            }
            u32x4 p0 = { g[0][0], g[0][1], g[0][2], g[0][3] };
            u32x4 p1 = { g[1][0], g[1][1], g[1][2], g[1][3] };
            bP[u][0] = __builtin_bit_cast(bf16x8, p0);
            bP[u][1] = __builtin_bit_cast(bf16x8, p1);
        }

        __builtin_amdgcn_s_setprio(1);
        // l partial: lacc += 1^T P
        lacc[0] = __builtin_amdgcn_mfma_f32_16x16x32_bf16(ones, bP[0][0], lacc[0], 0,0,0);
        lacc[0] = __builtin_amdgcn_mfma_f32_16x16x32_bf16(ones, bP[0][1], lacc[0], 0,0,0);
        lacc[1] = __builtin_amdgcn_mfma_f32_16x16x32_bf16(ones, bP[1][0], lacc[1], 0,0,0);
        lacc[1] = __builtin_amdgcn_mfma_f32_16x16x32_bf16(ones, bP[1][1], lacc[1], 0,0,0);

        // PV partial: O^T[64d][32q] += V^T P, V-frag reused across q-strips
        #pragma unroll
        for (int dt = 0; dt < 4; ++dt) {
            int drow = dt * 16 + m16;
            bf16x8 v0 = *(const bf16x8*)&vc[drow * 64 + ((quad ^ (drow & 7)) * 8)];
            bf16x8 v1 = *(const bf16x8*)&vc[drow * 64 + (((4 + quad) ^ (drow & 7)) * 8)];
            O[0][dt] = __builtin_amdgcn_mfma_f32_16x16x32_bf16(v0, bP[0][0], O[0][dt], 0,0,0);
            O[0][dt] = __builtin_amdgcn_mfma_f32_16x16x32_bf16(v1, bP[0][1], O[0][dt], 0,0,0);
            O[1][dt] = __builtin_amdgcn_mfma_f32_16x16x32_bf16(v0, bP[1][0], O[1][dt], 0,0,0);
            O[1][dt] = __builtin_amdgcn_mfma_f32_16x16x32_bf16(v1, bP[1][1], O[1][dt], 0,0,0);
        }
        __builtin_amdgcn_s_setprio(0);

        mbC0 = mbN0; mbC1 = mbN1;
    }

    // --- merge the two k-parity partials (group B -> LDS, group A adds) ---
    __syncthreads();
    float* sM = (float*)sAll;   // planes: 8 x [256 lanes x f32x4] + l: 256 x 2 f32 = 34 KB
    if (grp == 1) {
        #pragma unroll
        for (int u = 0; u < 2; ++u)
            #pragma unroll
            for (int dt = 0; dt < 4; ++dt)
                *(f32x4*)&sM[((u * 4 + dt) * 256 + wq * 64 + lane) * 4] = O[u][dt];
        sM[8192 + (wq * 64 + lane) * 2 + 0] = lacc[0][0];
        sM[8192 + (wq * 64 + lane) * 2 + 1] = lacc[1][0];
    }
    __syncthreads();
    if (grp == 0) {
        float l[2];
        l[0] = lacc[0][0] + sM[8192 + (wq * 64 + lane) * 2 + 0];
        l[1] = lacc[1][0] + sM[8192 + (wq * 64 + lane) * 2 + 1];
        #pragma unroll
        for (int u = 0; u < 2; ++u) {
            float inv = 1.f / l[u];
            size_t base = ((size_t)(b * SL + q0 + wq * 32 + u * 16 + m16)) * EMB + h * HD + quad * 4;
            #pragma unroll
            for (int dt = 0; dt < 4; ++dt) {
                f32x4 part = *(const f32x4*)&sM[((u * 4 + dt) * 256 + wq * 64 + lane) * 4];
                f32x4 o = O[u][dt] + part;
                uint2 ow = { cvtpk(o[0] * inv, o[1] * inv),
                             cvtpk(o[2] * inv, o[3] * inv) };
                *(uint2*)&Oa[base + dt * 16] = ow;
            }
        }
    }
}

// ---------------- Projection v3: C[4096][1024] = A_bf16 @ W_bf16^T + bias ----------------
// (unchanged from R8 — depth-2 counted-vmcnt pipeline)
__global__ __launch_bounds__(256, 2) void proj_mfma(
    const unsigned short* __restrict__ A, const unsigned short* __restrict__ Wb,
    const float* __restrict__ bias, float* __restrict__ C)
{
    const int lin = blockIdx.x;
    const int xcd = lin & 7, idx = lin >> 3;
    const int m0 = (xcd * 4 + (idx >> 4)) * 128;   // 32 m-tiles
    const int n0 = (idx & 15) * 64;                // 16 n-tiles
    const int tid = threadIdx.x;
    const int w = tid >> 6, lane = tid & 63;
    const int m16 = lane & 15, quad = lane >> 4;
    const int lr = lane >> 3, lc = lane & 7;
    const int wm = (w >> 1) * 64, wn = (w & 1) * 32;

    __shared__ __align__(16) unsigned short sA[3][128 * 64];
    __shared__ __align__(16) unsigned short sW[3][64 * 64];

    f32x4 acc[4][2] = {};

    #define PSTAGE(IT, BI)                                                        \
    {                                                                             \
        const int e0_ = (IT) * 64;                                                \
        _Pragma("unroll")                                                         \
        for (int i_ = 0; i_ < 4; ++i_) {                                          \
            int r_ = w * 32 + i_ * 8;                                             \
            gload_lds16(&A[(size_t)(m0 + r_ + lr) * EMB + e0_ + (lc ^ lr) * 8],   \
                        &sA[BI][r_ * 64]);                                        \
        }                                                                         \
        _Pragma("unroll")                                                         \
        for (int i_ = 0; i_ < 2; ++i_) {                                          \
            int r_ = w * 16 + i_ * 8;                                             \
            gload_lds16(&Wb[(size_t)(n0 + r_ + lr) * EMB + e0_ + (lc ^ lr) * 8],  \
                        &sW[BI][r_ * 64]);                                        \
        }                                                                         \
    }

    PSTAGE(0, 0)
    MEMPIN();          // pin issue order: it0's 6 strictly older than it1's 6
    PSTAGE(1, 1)
    MEMPIN();

    for (int it = 0; it < 16; ++it) {
        if (it < 15) { VMW(6); } else { VMW(0); }   // my 6 for this iter retired
        __builtin_amdgcn_s_barrier();
        __builtin_amdgcn_sched_barrier(0);

        if (it < 14) {
            const int bn = (it + 2) % 3;
            PSTAGE(it + 2, bn)
            MEMPIN();
        }

        const int bf = it % 3;
        #pragma unroll
        for (int hh = 0; hh < 2; ++hh) {
            bf16x8 af[4], bw[2];
            #pragma unroll
            for (int mt = 0; mt < 4; ++mt) {
                int r = wm + mt * 16 + m16;
                af[mt] = *(const bf16x8*)&sA[bf][r * 64 + (((hh * 4 + quad) ^ (r & 7)) * 8)];
            }
            #pragma unroll
            for (int nt = 0; nt < 2; ++nt) {
                int r = wn + nt * 16 + m16;
                bw[nt] = *(const bf16x8*)&sW[bf][r * 64 + (((hh * 4 + quad) ^ (r & 7)) * 8)];
            }
            #pragma unroll
            for (int mt = 0; mt < 4; ++mt)
                #pragma unroll
                for (int nt = 0; nt < 2; ++nt)
                    acc[mt][nt] = __builtin_amdgcn_mfma_f32_16x16x32_bf16(af[mt], bw[nt], acc[mt][nt], 0,0,0);
        }
    }

    #pragma unroll
    for (int nt = 0; nt < 2; ++nt) {
        float bv = bias[n0 + wn + nt * 16 + m16];
        #pragma unroll
        for (int mt = 0; mt < 4; ++mt) {
            size_t row = (size_t)(m0 + wm + mt * 16 + quad * 4);
            #pragma unroll
            for (int rg = 0; rg < 4; ++rg)
                C[(row + rg) * EMB + n0 + wn + nt * 16 + m16] = acc[mt][nt][rg] + bv;
        }
    }
}

extern "C" void kernel_launch(void* const* d_in, const int* in_sizes, int n_in,
                              void* d_out, int out_size, void* d_ws, size_t ws_size,
                              hipStream_t stream) {
    const float* Q    = (const float*)d_in[0];
    const float* K    = (const float*)d_in[1];
    const float* V    = (const float*)d_in[2];
    const int*   mask = (const int*)  d_in[3];
    const float* W    = (const float*)d_in[4];
    const float* bias = (const float*)d_in[5];

    unsigned short* Oa = (unsigned short*)d_ws;                              // 8.39 MB
    unsigned short* Wb = Oa + (size_t)NB * SL * EMB;                         // 2.10 MB
    unsigned long long* Mbt = (unsigned long long*)(Wb + (size_t)EMB * EMB); // 0.52 MB
    unsigned short* Vt = (unsigned short*)(Mbt + (size_t)NB * 16 * SL);      // 8.39 MB
    unsigned short* Kb = Vt + (size_t)NB * NH * HD * SL;                     // 8.39 MB

    prep<<<7168, 256, 0, stream>>>(W, Wb, K, Kb, V, Vt, mask, Mbt);
    attn_mfma<<<512, 512, 0, stream>>>(Q, Kb, Vt, Mbt, Oa);
    proj_mfma<<<512, 256, 0, stream>>>(Oa, Wb, bias, (float*)d_out);
}